// Round 1
// baseline (397.614 us; speedup 1.0000x reference)
//
#include <hip/hip_runtime.h>
#include <cstdint>
#include <cstddef>

#define B_ 4
#define N_ 8192
#define S_ 2048
#define M_ 32768   // B_*N_

typedef short bf16x8 __attribute__((ext_vector_type(8)));
typedef float f32x4 __attribute__((ext_vector_type(4)));

__device__ __forceinline__ float bf2f(unsigned short u) {
  union { unsigned int i; float f; } v; v.i = ((unsigned int)u) << 16; return v.f;
}
__device__ __forceinline__ unsigned short f2bf(float f) {
  union { float f; unsigned int i; } v; v.f = f;
  return (unsigned short)((v.i + 0x7FFFu + ((v.i >> 16) & 1u)) >> 16);
}

// ---------------- pack weights f32 -> bf16 (Wf 256x384, W1 256x256, W2 256x256) ----
__global__ void pack_weights(const float* __restrict__ Wf, const float* __restrict__ W1,
                             const float* __restrict__ W2, unsigned short* __restrict__ out) {
  int i = blockIdx.x * 256 + threadIdx.x;   // grid covers exactly 229376
  float v;
  if (i < 98304)       v = Wf[i];
  else if (i < 163840) v = W1[i - 98304];
  else                 v = W2[i - 163840];
  out[i] = f2bf(v);
}

// ---------------- tiled transpose: src [B][C][Nsp] f32 -> dst rows [(b*Nsp+n)*ldo + coff + c] bf16
__global__ void transpose_to_bf16(const float* __restrict__ src, unsigned short* __restrict__ dst,
                                  int C, int Nsp, int ldo, int coff) {
  __shared__ float t[32][33];
  int b = blockIdx.z;
  int n0 = blockIdx.x * 32, c0 = blockIdx.y * 32;
  int x = threadIdx.x, y = threadIdx.y;
  const float* s = src + ((size_t)b * C + c0) * Nsp + n0;
#pragma unroll
  for (int k = 0; k < 4; ++k)
    t[y + k * 8][x] = s[(size_t)(y + k * 8) * Nsp + x];
  __syncthreads();
#pragma unroll
  for (int k = 0; k < 4; ++k) {
    int n = n0 + y + k * 8;
    dst[((size_t)b * Nsp + n) * ldo + coff + c0 + x] = f2bf(t[x][y + k * 8]);
  }
}

// ---------------- 3-NN + inverse-distance interpolation ----------------
// grid (N_/256, B_), block 256. Fills new_points[:, 128:384] (bf16 rows of length 384).
__global__ __launch_bounds__(256) void knn_interp_kernel(
    const float* __restrict__ xyz1, const float* __restrict__ xyz2,
    const unsigned short* __restrict__ p2t, unsigned short* __restrict__ np) {
  __shared__ float sx[S_], sy[S_], sz[S_];
  __shared__ float sw[256][3];
  __shared__ int   sidx[256][3];
  int t = threadIdx.x;
  int b = blockIdx.y;
  for (int i = t; i < S_; i += 256) {
    const float* p = xyz2 + ((size_t)b * S_ + i) * 3;
    sx[i] = p[0]; sy[i] = p[1]; sz[i] = p[2];
  }
  __syncthreads();
  int n = blockIdx.x * 256 + t;
  const float* q = xyz1 + ((size_t)b * N_ + n) * 3;
  float px = q[0], py = q[1], pz = q[2];
  float d0 = 1e30f, d1 = 1e30f, d2 = 1e30f;
  int i0 = 0, i1 = 0, i2 = 0;
  for (int s = 0; s < S_; ++s) {
    float dx = px - sx[s], dy = py - sy[s], dz = pz - sz[s];
    float d = dx * dx + dy * dy + dz * dz;
    if (d < d2) {
      if (d < d1) {
        d2 = d1; i2 = i1;
        if (d < d0) { d1 = d0; i1 = i0; d0 = d; i0 = s; }
        else        { d1 = d;  i1 = s; }
      } else { d2 = d; i2 = s; }
    }
  }
  float r0 = 1.f / (d0 + 1e-8f), r1 = 1.f / (d1 + 1e-8f), r2 = 1.f / (d2 + 1e-8f);
  float rs = 1.f / (r0 + r1 + r2);
  sw[t][0] = r0 * rs; sw[t][1] = r1 * rs; sw[t][2] = r2 * rs;
  sidx[t][0] = i0; sidx[t][1] = i1; sidx[t][2] = i2;
  __syncthreads();
  int lane = t & 63, wave = t >> 6;
  for (int p = wave; p < 256; p += 4) {
    float w0 = sw[p][0], w1 = sw[p][1], w2 = sw[p][2];
    const ushort4* g0 = (const ushort4*)(p2t + ((size_t)b * S_ + sidx[p][0]) * 256) + lane;
    const ushort4* g1 = (const ushort4*)(p2t + ((size_t)b * S_ + sidx[p][1]) * 256) + lane;
    const ushort4* g2 = (const ushort4*)(p2t + ((size_t)b * S_ + sidx[p][2]) * 256) + lane;
    ushort4 a = *g0, c = *g1, e = *g2;
    ushort4 o;
    o.x = f2bf(w0 * bf2f(a.x) + w1 * bf2f(c.x) + w2 * bf2f(e.x));
    o.y = f2bf(w0 * bf2f(a.y) + w1 * bf2f(c.y) + w2 * bf2f(e.y));
    o.z = f2bf(w0 * bf2f(a.z) + w1 * bf2f(c.z) + w2 * bf2f(e.z));
    o.w = f2bf(w0 * bf2f(a.w) + w1 * bf2f(c.w) + w2 * bf2f(e.w));
    int nn = blockIdx.x * 256 + p;
    *((ushort4*)(np + ((size_t)b * N_ + nn) * 384 + 128) + lane) = o;
  }
}

// ---------------- bf16 GEMM (m97 structure): C[M][256] = A[M][K] * W[256][K]^T ----
// grid (M/128, 256/128), block 256 (4 waves, 2x2), BK=64, 16x16x32 bf16 MFMA.
__global__ __launch_bounds__(256) void gemm_bt(const unsigned short* __restrict__ A,
                                               const unsigned short* __restrict__ Bw,
                                               float* __restrict__ C, int K) {
  __shared__ unsigned short As[128 * 64];
  __shared__ unsigned short Bs[128 * 64];
  int tid = threadIdx.x;
  int lane = tid & 63, wave = tid >> 6;
  int wr = wave >> 1, wc = wave & 1;
  size_t m0 = (size_t)blockIdx.x * 128;
  int n0 = blockIdx.y * 128;
  int lr = lane & 15, lk = lane >> 4;
  f32x4 acc[4][4] = {};

  for (int kt = 0; kt < K; kt += 64) {
#pragma unroll
    for (int i = 0; i < 4; ++i) {
      int ch = i * 256 + tid;
      int row = ch >> 3;
      int col = (ch & 7) * 8;
      __builtin_amdgcn_global_load_lds(
          (const __attribute__((address_space(1))) void*)(A + (m0 + row) * K + kt + col),
          (__attribute__((address_space(3))) void*)(As + ch * 8), 16, 0, 0);
    }
#pragma unroll
    for (int i = 0; i < 4; ++i) {
      int ch = i * 256 + tid;
      int row = ch >> 3;
      int col = (ch & 7) * 8;
      __builtin_amdgcn_global_load_lds(
          (const __attribute__((address_space(1))) void*)(Bw + (size_t)(n0 + row) * K + kt + col),
          (__attribute__((address_space(3))) void*)(Bs + ch * 8), 16, 0, 0);
    }
    __syncthreads();   // drains vmcnt before barrier (compiler-inserted)

    bf16x8 af[4][2], bf[4][2];
#pragma unroll
    for (int m = 0; m < 4; ++m)
#pragma unroll
      for (int kk = 0; kk < 2; ++kk)
        af[m][kk] = *(const bf16x8*)(As + (wr * 64 + m * 16 + lr) * 64 + kk * 32 + lk * 8);
#pragma unroll
    for (int nn = 0; nn < 4; ++nn)
#pragma unroll
      for (int kk = 0; kk < 2; ++kk)
        bf[nn][kk] = *(const bf16x8*)(Bs + (wc * 64 + nn * 16 + lr) * 64 + kk * 32 + lk * 8);

#pragma unroll
    for (int m = 0; m < 4; ++m)
#pragma unroll
      for (int nn = 0; nn < 4; ++nn)
#pragma unroll
        for (int kk = 0; kk < 2; ++kk)
          acc[m][nn] = __builtin_amdgcn_mfma_f32_16x16x32_bf16(af[m][kk], bf[nn][kk], acc[m][nn], 0, 0, 0);
    __syncthreads();
  }

  // C/D layout (m89): col = lane&15, row = (lane>>4)*4 + j
#pragma unroll
  for (int m = 0; m < 4; ++m) {
    size_t row = m0 + wr * 64 + m * 16 + lk * 4;
#pragma unroll
    for (int j = 0; j < 4; ++j) {
      float* cr = C + (row + j) * 256 + n0 + wc * 64 + lr;
#pragma unroll
      for (int nn = 0; nn < 4; ++nn)
        cr[nn * 16] = acc[m][nn][j];
    }
  }
}

// ---------------- per-channel sum / sumsq over rows of X [M][256] ----------------
// grid 128 (256 rows each), block 256 (thread = channel). sums[0:256]=sum, [256:512]=sumsq.
__global__ void col_stats(const float* __restrict__ X, float* __restrict__ sums) {
  int c = threadIdx.x;
  size_t r0 = (size_t)blockIdx.x * 256;
  float s0 = 0, s1 = 0, s2 = 0, s3 = 0, q0 = 0, q1 = 0, q2 = 0, q3 = 0;
  for (int r = 0; r < 256; r += 4) {
    float v0 = X[(r0 + r + 0) * 256 + c];
    float v1 = X[(r0 + r + 1) * 256 + c];
    float v2 = X[(r0 + r + 2) * 256 + c];
    float v3 = X[(r0 + r + 3) * 256 + c];
    s0 += v0; q0 += v0 * v0;
    s1 += v1; q1 += v1 * v1;
    s2 += v2; q2 += v2 * v2;
    s3 += v3; q3 += v3 * v3;
  }
  atomicAdd(&sums[c], s0 + s1 + s2 + s3);
  atomicAdd(&sums[256 + c], q0 + q1 + q2 + q3);
}

// ---------------- BN (train) + ReLU + cast bf16: Y[M][256] ----------------
__global__ void bn_relu_kernel(const float* __restrict__ X, const float* __restrict__ sums,
                               const float* __restrict__ g, const float* __restrict__ be,
                               unsigned short* __restrict__ Y) {
  __shared__ float sc[256], sh[256];
  int t = threadIdx.x;
  {
    float s = sums[t], q = sums[256 + t];
    float m = s * (1.0f / 32768.0f);
    float v = q * (1.0f / 32768.0f) - m * m;
    float scale = g[t] * rsqrtf(v + 1e-5f);
    sc[t] = scale; sh[t] = be[t] - m * scale;
  }
  __syncthreads();
  const float4* X4 = (const float4*)X;
  ushort4* Y4 = (ushort4*)Y;
  for (size_t i = (size_t)blockIdx.x * 256 + t; i < (size_t)M_ * 64; i += 2048 * 256) {
    float4 x = X4[i];
    int c0 = (int)((i * 4) & 255);
    ushort4 o;
    o.x = f2bf(fmaxf(x.x * sc[c0 + 0] + sh[c0 + 0], 0.f));
    o.y = f2bf(fmaxf(x.y * sc[c0 + 1] + sh[c0 + 1], 0.f));
    o.z = f2bf(fmaxf(x.z * sc[c0 + 2] + sh[c0 + 2], 0.f));
    o.w = f2bf(fmaxf(x.w * sc[c0 + 3] + sh[c0 + 3], 0.f));
    Y4[i] = o;
  }
}

// ---------------- final: out[b][o][n] = relu(x + BN2(z)), tiled transpose ----------------
// grid (M/64, 256/64), block 256.
__global__ void final_kernel(const float* __restrict__ Z, const unsigned short* __restrict__ Xb,
                             const float* __restrict__ sums2, const float* __restrict__ g2,
                             const float* __restrict__ be2, float* __restrict__ out) {
  __shared__ float sc[64], sh[64];
  __shared__ float tile[64 * 65];
  int t = threadIdx.x;
  int o0 = blockIdx.y * 64;
  if (t < 64) {
    int c = o0 + t;
    float s = sums2[c], q = sums2[256 + c];
    float m = s * (1.0f / 32768.0f);
    float v = q * (1.0f / 32768.0f) - m * m;
    float scale = g2[c] * rsqrtf(v + 1e-5f);
    sc[t] = scale; sh[t] = be2[c] - m * scale;
  }
  __syncthreads();
  size_t m0 = (size_t)blockIdx.x * 64;
  int rl = t >> 4, cq = t & 15;
#pragma unroll
  for (int rr = 0; rr < 4; ++rr) {
    int row = rr * 16 + rl;
    size_t base = (m0 + row) * 256 + o0 + cq * 4;
    float4 z = *(const float4*)(Z + base);
    ushort4 x = *(const ushort4*)(Xb + base);
    int c = cq * 4;
    tile[row * 65 + c + 0] = fmaxf(z.x * sc[c + 0] + sh[c + 0] + bf2f(x.x), 0.f);
    tile[row * 65 + c + 1] = fmaxf(z.y * sc[c + 1] + sh[c + 1] + bf2f(x.y), 0.f);
    tile[row * 65 + c + 2] = fmaxf(z.z * sc[c + 2] + sh[c + 2] + bf2f(x.z), 0.f);
    tile[row * 65 + c + 3] = fmaxf(z.w * sc[c + 3] + sh[c + 3] + bf2f(x.w), 0.f);
  }
  __syncthreads();
  int b = (int)(m0 >> 13);
  int nbase = (int)(m0 & 8191);
  int orow = t >> 4, nq = t & 15;
#pragma unroll
  for (int ov = 0; ov < 4; ++ov) {
    int o = ov * 16 + orow;
    float4 v;
    v.x = tile[(nq * 4 + 0) * 65 + o];
    v.y = tile[(nq * 4 + 1) * 65 + o];
    v.z = tile[(nq * 4 + 2) * 65 + o];
    v.w = tile[(nq * 4 + 3) * 65 + o];
    *(float4*)(out + ((size_t)(b * 256 + o0 + o)) * 8192 + nbase + nq * 4) = v;
  }
}

extern "C" void kernel_launch(void* const* d_in, const int* in_sizes, int n_in,
                              void* d_out, int out_size, void* d_ws, size_t ws_size,
                              hipStream_t stream) {
  const float* xyz1    = (const float*)d_in[0];
  const float* xyz2    = (const float*)d_in[1];
  const float* points1 = (const float*)d_in[2];
  const float* points2 = (const float*)d_in[3];
  const float* W_fuse  = (const float*)d_in[4];
  // biases d_in[5], d_in[9], d_in[13] cancel exactly under training-mode BN
  const float* g_fuse  = (const float*)d_in[6];
  const float* be_fuse = (const float*)d_in[7];
  const float* W1      = (const float*)d_in[8];
  const float* g1      = (const float*)d_in[10];
  const float* be1     = (const float*)d_in[11];
  const float* W2      = (const float*)d_in[12];
  const float* g2      = (const float*)d_in[14];
  const float* be2     = (const float*)d_in[15];
  float* out = (float*)d_out;

  char* ws = (char*)d_ws;
  float* lin = (float*)ws;                   ws += (size_t)M_ * 256 * 4;   // 33.5 MB, reused 3x
  unsigned short* xb = (unsigned short*)ws;  ws += (size_t)M_ * 256 * 2;   // 16.8 MB
  unsigned short* np = (unsigned short*)ws;  ws += (size_t)M_ * 384 * 2;   // 25.2 MB (yb aliases np)
  unsigned short* yb = np;                                                  // np dead after fuse GEMM
  unsigned short* p2t = (unsigned short*)ws; ws += (size_t)B_ * S_ * 256 * 2; // 4.2 MB
  unsigned short* wb = (unsigned short*)ws;  ws += 229376 * 2;
  float* stats = (float*)ws;                 // 6*256 floats

  hipMemsetAsync(stats, 0, 6 * 256 * sizeof(float), stream);
  pack_weights<<<896, 256, 0, stream>>>(W_fuse, W1, W2, wb);
  // points1 -> new_points[:, 0:128]
  transpose_to_bf16<<<dim3(256, 4, 4), dim3(32, 8), 0, stream>>>(points1, np, 128, N_, 384, 0);
  // points2 -> p2t [B][S][256]
  transpose_to_bf16<<<dim3(64, 8, 4), dim3(32, 8), 0, stream>>>(points2, p2t, 256, S_, 256, 0);
  // 3-NN interp -> new_points[:, 128:384]
  knn_interp_kernel<<<dim3(N_ / 256, B_), 256, 0, stream>>>(xyz1, xyz2, p2t, np);
  // fuse layer
  gemm_bt<<<dim3(M_ / 128, 2), 256, 0, stream>>>(np, wb, lin, 384);
  col_stats<<<128, 256, 0, stream>>>(lin, stats);
  bn_relu_kernel<<<2048, 256, 0, stream>>>(lin, stats, g_fuse, be_fuse, xb);
  // residual block conv1
  gemm_bt<<<dim3(M_ / 128, 2), 256, 0, stream>>>(xb, wb + 98304, lin, 256);
  col_stats<<<128, 256, 0, stream>>>(lin, stats + 512);
  bn_relu_kernel<<<2048, 256, 0, stream>>>(lin, stats + 512, g1, be1, yb);
  // residual block conv2
  gemm_bt<<<dim3(M_ / 128, 2), 256, 0, stream>>>(yb, wb + 163840, lin, 256);
  col_stats<<<128, 256, 0, stream>>>(lin, stats + 1024);
  // BN2 + residual + relu + transpose to [B][256][N]
  final_kernel<<<dim3(M_ / 64, 4), 256, 0, stream>>>(lin, xb, stats + 1024, g2, be2, out);
}

// Round 2
// 166.395 us; speedup vs baseline: 2.3896x; 2.3896x over previous
//
#include <hip/hip_runtime.h>
#include <cstdint>
#include <cstddef>

#define B_ 4
#define N_ 8192
#define S_ 2048
#define M_ 32768   // B_*N_

typedef short bf16x8 __attribute__((ext_vector_type(8)));
typedef float f32x4 __attribute__((ext_vector_type(4)));

__device__ __forceinline__ float bf2f(unsigned short u) {
  union { unsigned int i; float f; } v; v.i = ((unsigned int)u) << 16; return v.f;
}
__device__ __forceinline__ unsigned short f2bf(float f) {
  union { float f; unsigned int i; } v; v.f = f;
  return (unsigned short)((v.i + 0x7FFFu + ((v.i >> 16) & 1u)) >> 16);
}

// ---------------- pack weights f32 -> bf16 (Wf 256x384, W1 256x256, W2 256x256) ----
__global__ void pack_weights(const float* __restrict__ Wf, const float* __restrict__ W1,
                             const float* __restrict__ W2, unsigned short* __restrict__ out) {
  int i = blockIdx.x * 256 + threadIdx.x;   // grid covers exactly 229376
  float v;
  if (i < 98304)       v = Wf[i];
  else if (i < 163840) v = W1[i - 98304];
  else                 v = W2[i - 163840];
  out[i] = f2bf(v);
}

// ---------------- tiled transpose: src [B][C][Nsp] f32 -> dst rows [(b*Nsp+n)*ldo + coff + c] bf16
__global__ void transpose_to_bf16(const float* __restrict__ src, unsigned short* __restrict__ dst,
                                  int C, int Nsp, int ldo, int coff) {
  __shared__ float t[32][33];
  int b = blockIdx.z;
  int n0 = blockIdx.x * 32, c0 = blockIdx.y * 32;
  int x = threadIdx.x, y = threadIdx.y;
  const float* s = src + ((size_t)b * C + c0) * Nsp + n0;
#pragma unroll
  for (int k = 0; k < 4; ++k)
    t[y + k * 8][x] = s[(size_t)(y + k * 8) * Nsp + x];
  __syncthreads();
#pragma unroll
  for (int k = 0; k < 4; ++k) {
    int n = n0 + y + k * 8;
    dst[((size_t)b * Nsp + n) * ldo + coff + c0 + x] = f2bf(t[x][y + k * 8]);
  }
}

// ---------------- 3-NN + inverse-distance interpolation ----------------
// grid (N_/32, B_), block 256. 8 lanes cooperate per query point (each scans S/8
// candidates, branchless top-3, then 3-stage shfl_xor merge with u64 keys so ties
// break toward the lower index, matching top_k stability).
__global__ __launch_bounds__(256) void knn_interp_kernel(
    const float* __restrict__ xyz1, const float* __restrict__ xyz2,
    const unsigned short* __restrict__ p2t, unsigned short* __restrict__ np) {
  __shared__ float4 sp[S_];          // 32 KB candidate points (xyz, pad)
  __shared__ float sw[32][3];
  __shared__ int   sidx[32][3];
  int t = threadIdx.x;
  int b = blockIdx.y;
  const float* xb = xyz2 + (size_t)b * S_ * 3;
  for (int i = t; i < S_; i += 256)
    sp[i] = make_float4(xb[3 * i], xb[3 * i + 1], xb[3 * i + 2], 0.f);
  __syncthreads();

  int lane = t & 63, wave = t >> 6;
  int sub = lane & 7;            // which 1/8 of candidate set
  int pib = wave * 8 + (lane >> 3);  // point in block (0..31)
  int n = blockIdx.x * 32 + pib;
  const float* q = xyz1 + ((size_t)b * N_ + n) * 3;
  float px = q[0], py = q[1], pz = q[2];

  float d0 = 1e30f, d1 = 1e30f, d2 = 1e30f;
  int i0 = S_, i1 = S_, i2 = S_;
  int s = sub;
#pragma unroll 4
  for (int i = 0; i < S_ / 8; ++i) {
    float4 c = sp[s];
    float dx = px - c.x, dy = py - c.y, dz = pz - c.z;
    float d = fmaf(dx, dx, fmaf(dy, dy, dz * dz));
    bool b0 = d < d0, b1 = d < d1, b2 = d < d2;
    d2 = b1 ? d1 : (b2 ? d : d2);
    i2 = b1 ? i1 : (b2 ? s : i2);
    d1 = b0 ? d0 : (b1 ? d : d1);
    i1 = b0 ? i0 : (b1 ? s : i1);
    d0 = b0 ? d : d0;
    i0 = b0 ? s : i0;
    s += 8;
  }

  // build sortable keys: dist (nonneg f32 -> uint order) then index (tie-break low)
  unsigned long long k0 = ((unsigned long long)__float_as_uint(d0) << 32) | (unsigned int)i0;
  unsigned long long k1 = ((unsigned long long)__float_as_uint(d1) << 32) | (unsigned int)i1;
  unsigned long long k2 = ((unsigned long long)__float_as_uint(d2) << 32) | (unsigned int)i2;
#pragma unroll
  for (int m = 1; m <= 4; m <<= 1) {
    unsigned long long a0 = __shfl_xor(k0, m, 64);
    unsigned long long a1 = __shfl_xor(k1, m, 64);
    unsigned long long a2 = __shfl_xor(k2, m, 64);
    unsigned long long lo0 = k0 < a0 ? k0 : a0, hi0 = k0 < a0 ? a0 : k0;
    unsigned long long lo1 = k1 < a1 ? k1 : a1, hi1 = k1 < a1 ? a1 : k1;
    unsigned long long lo2 = k2 < a2 ? k2 : a2;
    k0 = lo0;
    unsigned long long r1 = hi0 < lo1 ? hi0 : lo1;
    unsigned long long s1 = hi0 < lo1 ? lo1 : hi0;      // max(hi0, lo1)
    unsigned long long u  = hi1 < lo2 ? hi1 : lo2;      // min(max1, min2)
    k1 = r1;
    k2 = s1 < u ? s1 : u;
  }
  if (sub == 0) {
    float e0 = __uint_as_float((unsigned int)(k0 >> 32));
    float e1 = __uint_as_float((unsigned int)(k1 >> 32));
    float e2 = __uint_as_float((unsigned int)(k2 >> 32));
    float r0 = 1.f / (e0 + 1e-8f), r1 = 1.f / (e1 + 1e-8f), r2 = 1.f / (e2 + 1e-8f);
    float rs = 1.f / (r0 + r1 + r2);
    sw[pib][0] = r0 * rs; sw[pib][1] = r1 * rs; sw[pib][2] = r2 * rs;
    sidx[pib][0] = (int)(unsigned int)k0;
    sidx[pib][1] = (int)(unsigned int)k1;
    sidx[pib][2] = (int)(unsigned int)k2;
  }
  __syncthreads();

  // gather + weighted sum -> new_points[:, 128:384]
  for (int p = wave; p < 32; p += 4) {
    float w0 = sw[p][0], w1 = sw[p][1], w2 = sw[p][2];
    const ushort4* g0 = (const ushort4*)(p2t + ((size_t)b * S_ + sidx[p][0]) * 256) + lane;
    const ushort4* g1 = (const ushort4*)(p2t + ((size_t)b * S_ + sidx[p][1]) * 256) + lane;
    const ushort4* g2 = (const ushort4*)(p2t + ((size_t)b * S_ + sidx[p][2]) * 256) + lane;
    ushort4 a = *g0, c = *g1, e = *g2;
    ushort4 o;
    o.x = f2bf(w0 * bf2f(a.x) + w1 * bf2f(c.x) + w2 * bf2f(e.x));
    o.y = f2bf(w0 * bf2f(a.y) + w1 * bf2f(c.y) + w2 * bf2f(e.y));
    o.z = f2bf(w0 * bf2f(a.z) + w1 * bf2f(c.z) + w2 * bf2f(e.z));
    o.w = f2bf(w0 * bf2f(a.w) + w1 * bf2f(c.w) + w2 * bf2f(e.w));
    int nn = blockIdx.x * 32 + p;
    *((ushort4*)(np + ((size_t)b * N_ + nn) * 384 + 128) + lane) = o;
  }
}

// ---------------- bf16 GEMM (m97 structure): C[M][256] = A[M][K] * W[256][K]^T ----
// grid (M/128, 256/128), block 256 (4 waves, 2x2), BK=64, 16x16x32 bf16 MFMA.
__global__ __launch_bounds__(256) void gemm_bt(const unsigned short* __restrict__ A,
                                               const unsigned short* __restrict__ Bw,
                                               float* __restrict__ C, int K) {
  __shared__ unsigned short As[128 * 64];
  __shared__ unsigned short Bs[128 * 64];
  int tid = threadIdx.x;
  int lane = tid & 63, wave = tid >> 6;
  int wr = wave >> 1, wc = wave & 1;
  size_t m0 = (size_t)blockIdx.x * 128;
  int n0 = blockIdx.y * 128;
  int lr = lane & 15, lk = lane >> 4;
  f32x4 acc[4][4] = {};

  for (int kt = 0; kt < K; kt += 64) {
#pragma unroll
    for (int i = 0; i < 4; ++i) {
      int ch = i * 256 + tid;
      int row = ch >> 3;
      int col = (ch & 7) * 8;
      __builtin_amdgcn_global_load_lds(
          (const __attribute__((address_space(1))) void*)(A + (m0 + row) * K + kt + col),
          (__attribute__((address_space(3))) void*)(As + ch * 8), 16, 0, 0);
    }
#pragma unroll
    for (int i = 0; i < 4; ++i) {
      int ch = i * 256 + tid;
      int row = ch >> 3;
      int col = (ch & 7) * 8;
      __builtin_amdgcn_global_load_lds(
          (const __attribute__((address_space(1))) void*)(Bw + (size_t)(n0 + row) * K + kt + col),
          (__attribute__((address_space(3))) void*)(Bs + ch * 8), 16, 0, 0);
    }
    __syncthreads();

    bf16x8 af[4][2], bf[4][2];
#pragma unroll
    for (int m = 0; m < 4; ++m)
#pragma unroll
      for (int kk = 0; kk < 2; ++kk)
        af[m][kk] = *(const bf16x8*)(As + (wr * 64 + m * 16 + lr) * 64 + kk * 32 + lk * 8);
#pragma unroll
    for (int nn = 0; nn < 4; ++nn)
#pragma unroll
      for (int kk = 0; kk < 2; ++kk)
        bf[nn][kk] = *(const bf16x8*)(Bs + (wc * 64 + nn * 16 + lr) * 64 + kk * 32 + lk * 8);

#pragma unroll
    for (int m = 0; m < 4; ++m)
#pragma unroll
      for (int nn = 0; nn < 4; ++nn)
#pragma unroll
        for (int kk = 0; kk < 2; ++kk)
          acc[m][nn] = __builtin_amdgcn_mfma_f32_16x16x32_bf16(af[m][kk], bf[nn][kk], acc[m][nn], 0, 0, 0);
    __syncthreads();
  }

  // C/D layout (m89): col = lane&15, row = (lane>>4)*4 + j
#pragma unroll
  for (int m = 0; m < 4; ++m) {
    size_t row = m0 + wr * 64 + m * 16 + lk * 4;
#pragma unroll
    for (int j = 0; j < 4; ++j) {
      float* cr = C + (row + j) * 256 + n0 + wc * 64 + lr;
#pragma unroll
      for (int nn = 0; nn < 4; ++nn)
        cr[nn * 16] = acc[m][nn][j];
    }
  }
}

// ---------------- per-channel sum / sumsq over rows of X [M][256] ----------------
__global__ void col_stats(const float* __restrict__ X, float* __restrict__ sums) {
  int c = threadIdx.x;
  size_t r0 = (size_t)blockIdx.x * 256;
  float s0 = 0, s1 = 0, s2 = 0, s3 = 0, q0 = 0, q1 = 0, q2 = 0, q3 = 0;
  for (int r = 0; r < 256; r += 4) {
    float v0 = X[(r0 + r + 0) * 256 + c];
    float v1 = X[(r0 + r + 1) * 256 + c];
    float v2 = X[(r0 + r + 2) * 256 + c];
    float v3 = X[(r0 + r + 3) * 256 + c];
    s0 += v0; q0 += v0 * v0;
    s1 += v1; q1 += v1 * v1;
    s2 += v2; q2 += v2 * v2;
    s3 += v3; q3 += v3 * v3;
  }
  atomicAdd(&sums[c], s0 + s1 + s2 + s3);
  atomicAdd(&sums[256 + c], q0 + q1 + q2 + q3);
}

// ---------------- BN (train) + ReLU + cast bf16: Y[M][256] ----------------
__global__ void bn_relu_kernel(const float* __restrict__ X, const float* __restrict__ sums,
                               const float* __restrict__ g, const float* __restrict__ be,
                               unsigned short* __restrict__ Y) {
  __shared__ float sc[256], sh[256];
  int t = threadIdx.x;
  {
    float s = sums[t], q = sums[256 + t];
    float m = s * (1.0f / 32768.0f);
    float v = q * (1.0f / 32768.0f) - m * m;
    float scale = g[t] * rsqrtf(v + 1e-5f);
    sc[t] = scale; sh[t] = be[t] - m * scale;
  }
  __syncthreads();
  const float4* X4 = (const float4*)X;
  ushort4* Y4 = (ushort4*)Y;
  for (size_t i = (size_t)blockIdx.x * 256 + t; i < (size_t)M_ * 64; i += 2048 * 256) {
    float4 x = X4[i];
    int c0 = (int)((i * 4) & 255);
    ushort4 o;
    o.x = f2bf(fmaxf(x.x * sc[c0 + 0] + sh[c0 + 0], 0.f));
    o.y = f2bf(fmaxf(x.y * sc[c0 + 1] + sh[c0 + 1], 0.f));
    o.z = f2bf(fmaxf(x.z * sc[c0 + 2] + sh[c0 + 2], 0.f));
    o.w = f2bf(fmaxf(x.w * sc[c0 + 3] + sh[c0 + 3], 0.f));
    Y4[i] = o;
  }
}

// ---------------- final: out[b][o][n] = relu(x + BN2(z)), tiled transpose ----------------
__global__ void final_kernel(const float* __restrict__ Z, const unsigned short* __restrict__ Xb,
                             const float* __restrict__ sums2, const float* __restrict__ g2,
                             const float* __restrict__ be2, float* __restrict__ out) {
  __shared__ float sc[64], sh[64];
  __shared__ float tile[64 * 65];
  int t = threadIdx.x;
  int o0 = blockIdx.y * 64;
  if (t < 64) {
    int c = o0 + t;
    float s = sums2[c], q = sums2[256 + c];
    float m = s * (1.0f / 32768.0f);
    float v = q * (1.0f / 32768.0f) - m * m;
    float scale = g2[c] * rsqrtf(v + 1e-5f);
    sc[t] = scale; sh[t] = be2[c] - m * scale;
  }
  __syncthreads();
  size_t m0 = (size_t)blockIdx.x * 64;
  int rl = t >> 4, cq = t & 15;
#pragma unroll
  for (int rr = 0; rr < 4; ++rr) {
    int row = rr * 16 + rl;
    size_t base = (m0 + row) * 256 + o0 + cq * 4;
    float4 z = *(const float4*)(Z + base);
    ushort4 x = *(const ushort4*)(Xb + base);
    int c = cq * 4;
    tile[row * 65 + c + 0] = fmaxf(z.x * sc[c + 0] + sh[c + 0] + bf2f(x.x), 0.f);
    tile[row * 65 + c + 1] = fmaxf(z.y * sc[c + 1] + sh[c + 1] + bf2f(x.y), 0.f);
    tile[row * 65 + c + 2] = fmaxf(z.z * sc[c + 2] + sh[c + 2] + bf2f(x.z), 0.f);
    tile[row * 65 + c + 3] = fmaxf(z.w * sc[c + 3] + sh[c + 3] + bf2f(x.w), 0.f);
  }
  __syncthreads();
  int b = (int)(m0 >> 13);
  int nbase = (int)(m0 & 8191);
  int orow = t >> 4, nq = t & 15;
#pragma unroll
  for (int ov = 0; ov < 4; ++ov) {
    int o = ov * 16 + orow;
    float4 v;
    v.x = tile[(nq * 4 + 0) * 65 + o];
    v.y = tile[(nq * 4 + 1) * 65 + o];
    v.z = tile[(nq * 4 + 2) * 65 + o];
    v.w = tile[(nq * 4 + 3) * 65 + o];
    *(float4*)(out + ((size_t)(b * 256 + o0 + o)) * 8192 + nbase + nq * 4) = v;
  }
}

extern "C" void kernel_launch(void* const* d_in, const int* in_sizes, int n_in,
                              void* d_out, int out_size, void* d_ws, size_t ws_size,
                              hipStream_t stream) {
  const float* xyz1    = (const float*)d_in[0];
  const float* xyz2    = (const float*)d_in[1];
  const float* points1 = (const float*)d_in[2];
  const float* points2 = (const float*)d_in[3];
  const float* W_fuse  = (const float*)d_in[4];
  // biases d_in[5], d_in[9], d_in[13] cancel exactly under training-mode BN
  const float* g_fuse  = (const float*)d_in[6];
  const float* be_fuse = (const float*)d_in[7];
  const float* W1      = (const float*)d_in[8];
  const float* g1      = (const float*)d_in[10];
  const float* be1     = (const float*)d_in[11];
  const float* W2      = (const float*)d_in[12];
  const float* g2      = (const float*)d_in[14];
  const float* be2     = (const float*)d_in[15];
  float* out = (float*)d_out;

  char* ws = (char*)d_ws;
  float* lin = (float*)ws;                   ws += (size_t)M_ * 256 * 4;   // 33.5 MB, reused 3x
  unsigned short* xb = (unsigned short*)ws;  ws += (size_t)M_ * 256 * 2;   // 16.8 MB
  unsigned short* np = (unsigned short*)ws;  ws += (size_t)M_ * 384 * 2;   // 25.2 MB (yb aliases np)
  unsigned short* yb = np;                                                  // np dead after fuse GEMM
  unsigned short* p2t = (unsigned short*)ws; ws += (size_t)B_ * S_ * 256 * 2; // 4.2 MB
  unsigned short* wb = (unsigned short*)ws;  ws += 229376 * 2;
  float* stats = (float*)ws;                 // 6*256 floats

  hipMemsetAsync(stats, 0, 6 * 256 * sizeof(float), stream);
  pack_weights<<<896, 256, 0, stream>>>(W_fuse, W1, W2, wb);
  // points1 -> new_points[:, 0:128]
  transpose_to_bf16<<<dim3(256, 4, 4), dim3(32, 8), 0, stream>>>(points1, np, 128, N_, 384, 0);
  // points2 -> p2t [B][S][256]
  transpose_to_bf16<<<dim3(64, 8, 4), dim3(32, 8), 0, stream>>>(points2, p2t, 256, S_, 256, 0);
  // 3-NN interp -> new_points[:, 128:384]
  knn_interp_kernel<<<dim3(N_ / 32, B_), 256, 0, stream>>>(xyz1, xyz2, p2t, np);
  // fuse layer
  gemm_bt<<<dim3(M_ / 128, 2), 256, 0, stream>>>(np, wb, lin, 384);
  col_stats<<<128, 256, 0, stream>>>(lin, stats);
  bn_relu_kernel<<<2048, 256, 0, stream>>>(lin, stats, g_fuse, be_fuse, xb);
  // residual block conv1
  gemm_bt<<<dim3(M_ / 128, 2), 256, 0, stream>>>(xb, wb + 98304, lin, 256);
  col_stats<<<128, 256, 0, stream>>>(lin, stats + 512);
  bn_relu_kernel<<<2048, 256, 0, stream>>>(lin, stats + 512, g1, be1, yb);
  // residual block conv2
  gemm_bt<<<dim3(M_ / 128, 2), 256, 0, stream>>>(yb, wb + 163840, lin, 256);
  col_stats<<<128, 256, 0, stream>>>(lin, stats + 1024);
  // BN2 + residual + relu + transpose to [B][256][N]
  final_kernel<<<dim3(M_ / 64, 4), 256, 0, stream>>>(lin, xb, stats + 1024, g2, be2, out);
}